// Round 1
// baseline (7600.123 us; speedup 1.0000x reference)
//
#include <hip/hip_runtime.h>

// Fused persistent-weight LSTM, fp32 I/O, split-bf16 MFMA. MI355X (gfx950).
//
// R4: dataflow seqlock replaces the chain counter barrier.
//  - h exchanged as one 8B agent-scope atomic per element: {tag=t+1 (hi32) |
//    pack2(bf16 hi, bf16 lo) (lo32)}. Readers poll the data words directly
//    until tag matches -> ONE IF round trip per step instead of three
//    (store-ack + counter-add + counter-poll). Double-buffer by t&1 is safe:
//    a writer cannot overwrite slot s (2 steps later) before all readers of
//    slot s finished, because its next-step poll needs their products.
//  - Wave specialization: waves 0-1 (K 0..511) depend only on x_t and stage/
//    convert it off the critical path; waves 2-3 (K 512..1023) poll h. Each
//    wave stages its OWN LDS region -> no staging barriers; single
//    __syncthreads per step (double-buffered xchg).
//  - A-planes XOR-swizzled (byte ^= (row&7)<<4, no pad): fragment reads and
//    h-staging writes 2-way (free); was 8-way on staging writes (2.5e8
//    conflict cycles).
//  - hbuf memset per launch (captured in graph): stale tags from a previous
//    launch can collide at t=TT-1 otherwise; tag 0 never matches.
//
// Numerics unchanged vs R3: v = hi + lo (bf16 each); acc += ah*wh + al*wh +
// ah*wl in fp32 MFMA accumulators (verified absmax 2e-3 vs threshold 1.66e-2).

typedef unsigned short u16;
typedef unsigned int   u32;
typedef unsigned long long u64;
typedef short bf16x8 __attribute__((ext_vector_type(8)));
typedef float f32x4  __attribute__((ext_vector_type(4)));

#define TT 512
#define BB 128
#define DD 512
#define HH 512

__device__ __forceinline__ float bf2f(u16 u) { return __uint_as_float(((u32)u) << 16); }
__device__ __forceinline__ u16 f2bf(float f) {
    u32 u = __float_as_uint(f);
    return (u16)((u + 0x7FFFu + ((u >> 16) & 1u)) >> 16);   // RNE
}
__device__ __forceinline__ u32 pack2(u16 a, u16 b) { return (u32)a | ((u32)b << 16); }
__device__ __forceinline__ float sigm(float x)  { return 1.0f / (1.0f + __expf(-x)); }
__device__ __forceinline__ float tanh_(float x) { return 1.0f - 2.0f / (1.0f + __expf(2.0f * x)); }

__launch_bounds__(256, 1)
__global__ void lstm_fused(const float* __restrict__ x,
                           const float* __restrict__ Wf, const float* __restrict__ bfv,
                           const float* __restrict__ Wi, const float* __restrict__ biv,
                           const float* __restrict__ Wg, const float* __restrict__ bgv,
                           const float* __restrict__ Wo, const float* __restrict__ bov,
                           float* __restrict__ out, u64* __restrict__ hbuf)
{
    // hi plane [16 rows][1024 cols] bf16 (32 KB) then lo plane at +0x8000.
    // Within-row byte offset is XOR-swizzled: off ^= (row&7)<<4.
    __shared__ __align__(16) u16   aPl[2 * 16 * 1024];
    __shared__ __align__(16) float xch[2][4 * 4 * 16 * 20];   // dbuf [wave][gate][col][row16+4]

    const int tid  = threadIdx.x;
    const int lane = tid & 63;
    const int wv   = tid >> 6;        // wave 0..3 : K-quarter owner
    const int l16  = lane & 15;
    const int quad = lane >> 4;
    const int blk  = blockIdx.x;
    const int mg   = blk & 7;         // row-group / chain id (XCD-affine heuristic)
    const int nb   = blk >> 3;        // hidden-col slice 0..31
    const int rowbase = mg * 16;
    const int kwb  = wv * 256;
    const bool isH = (wv >= 2);       // waves 2,3 own the h K-half

    // ---- one-time: persistent split-bf16 B fragments ----
    // frag elem j of (gate q, kstep s): W[k = kwb + s*32 + quad*8 + j][nb*16 + l16]
    const float* Wq[4] = { Wf, Wi, Wg, Wo };
    bf16x8 whi[4][8], wlo[4][8];
#pragma unroll
    for (int q = 0; q < 4; ++q) {
        const float* Wp = Wq[q] + (size_t)(kwb + quad * 8) * HH + nb * 16 + l16;
#pragma unroll
        for (int s = 0; s < 8; ++s)
#pragma unroll
            for (int j = 0; j < 8; ++j) {
                float wval = Wp[(size_t)(s * 32 + j) * HH];
                u16 h = f2bf(wval);
                whi[q][s][j] = (short)h;
                wlo[q][s][j] = (short)f2bf(wval - bf2f(h));
            }
    }

    // ---- elementwise mapping: (row er, col ec) of this block's 16x16 h-tile ----
    const int ec = tid & 15, er = tid >> 4;
    const int hcol = nb * 16 + ec;
    const float bias[4] = { bfv[hcol], biv[hcol], bgv[hcol], bov[hcol] };
    float cst = 0.0f;                 // c-state lives in a register all 512 steps
    const int gidx = (rowbase + er) * HH + hcol;
    u64* hout = hbuf + gidx;

    // ---- staging lane geometry (wave-private region: 16 rows x 256 cols) ----
    // h-waves: row = lane&15 (conflict-free swizzled writes, row-streamed hbuf reads)
    // x-waves: row = lane>>2 (better global coalescing; 4-way LDS write, off-path)
    const int srow = isH ? (lane & 15) : (lane >> 2);
    const int scb  = isH ? (lane >> 4) : (lane & 3);   // 64-col chunk within region

    char* aB = (char*)aPl;
    int wrA[8], rdA[8];
    {
        const int swzW = (srow & 7) << 4;
#pragma unroll
        for (int i = 0; i < 8; ++i)
            wrA[i] = srow * 2048 + wv * 512 + ((scb * 128 + i * 16) ^ swzW);
        const int swzR = (l16 & 7) << 4;
#pragma unroll
        for (int s = 0; s < 8; ++s)   // pre-XOR col = quad*8 + s*32 (matches W k-index)
            rdA[s] = l16 * 2048 + wv * 512 + ((quad * 16 + s * 64) ^ swzR);
    }

    const float* xptr = x + (size_t)(rowbase + srow) * DD + kwb + scb * 64;
    const u64*   hrow = hbuf + (size_t)(rowbase + srow) * HH
                             + (isH ? (kwb - 512) : 0) + scb * 64;

    for (int t = 0; t < TT; ++t) {
        // ---- stage own K-quarter of A = [x_t | h_{t-1}] (split hi/lo) ----
        if (!isH) {
            const float4* xs = (const float4*)xptr;
#pragma unroll
            for (int g = 0; g < 8; ++g) {
                float4 a = xs[2 * g], b = xs[2 * g + 1];
                u16 h0 = f2bf(a.x), h1 = f2bf(a.y), h2 = f2bf(a.z), h3 = f2bf(a.w);
                u16 h4 = f2bf(b.x), h5 = f2bf(b.y), h6 = f2bf(b.z), h7 = f2bf(b.w);
                uint4 H = { pack2(h0, h1), pack2(h2, h3), pack2(h4, h5), pack2(h6, h7) };
                uint4 L = { pack2(f2bf(a.x - bf2f(h0)), f2bf(a.y - bf2f(h1))),
                            pack2(f2bf(a.z - bf2f(h2)), f2bf(a.w - bf2f(h3))),
                            pack2(f2bf(b.x - bf2f(h4)), f2bf(b.y - bf2f(h5))),
                            pack2(f2bf(b.z - bf2f(h6)), f2bf(b.w - bf2f(h7))) };
                *(uint4*)(aB + wrA[g]) = H;
                *(uint4*)(aB + wrA[g] + 32768) = L;
            }
            xptr += (size_t)BB * DD;
        } else if (t == 0) {
            uint4 z = { 0u, 0u, 0u, 0u };
#pragma unroll
            for (int g = 0; g < 8; ++g) {
                *(uint4*)(aB + wrA[g]) = z;
                *(uint4*)(aB + wrA[g] + 32768) = z;
            }
        } else {
            // seqlock poll: 64 consecutive cols of one row, tag == t
            const u64* hp = hrow + (size_t)((t - 1) & 1) * (BB * HH);
            const u32 want = (u32)t;
            u64 v[64];
            for (;;) {
#pragma unroll
                for (int j = 0; j < 64; ++j)
                    v[j] = __hip_atomic_load(hp + j, __ATOMIC_RELAXED, __HIP_MEMORY_SCOPE_AGENT);
                u32 bad = 0;
#pragma unroll
                for (int j = 0; j < 64; ++j) bad |= ((u32)(v[j] >> 32)) ^ want;
                if (bad == 0) break;   // per-lane exit; re-reads of done lanes are stable
            }
#pragma unroll
            for (int g = 0; g < 8; ++g) {
                u32 p[8];
#pragma unroll
                for (int j = 0; j < 8; ++j) p[j] = (u32)v[g * 8 + j];
                uint4 H = { (p[0] & 0xFFFFu) | (p[1] << 16), (p[2] & 0xFFFFu) | (p[3] << 16),
                            (p[4] & 0xFFFFu) | (p[5] << 16), (p[6] & 0xFFFFu) | (p[7] << 16) };
                uint4 L = { (p[0] >> 16) | (p[1] & 0xFFFF0000u), (p[2] >> 16) | (p[3] & 0xFFFF0000u),
                            (p[4] >> 16) | (p[5] & 0xFFFF0000u), (p[6] >> 16) | (p[7] & 0xFFFF0000u) };
                *(uint4*)(aB + wrA[g]) = H;
                *(uint4*)(aB + wrA[g] + 32768) = L;
            }
        }

        // ---- MFMA: own K-quarter (wave-private LDS; lgkmcnt auto, no barrier) ----
        f32x4 acc[4];
#pragma unroll
        for (int q = 0; q < 4; ++q) acc[q] = (f32x4){0.f, 0.f, 0.f, 0.f};
#pragma unroll
        for (int s = 0; s < 8; ++s) {
            bf16x8 ah = *(const bf16x8*)(aB + rdA[s]);
            bf16x8 al = *(const bf16x8*)(aB + rdA[s] + 32768);
#pragma unroll
            for (int q = 0; q < 4; ++q) {
                acc[q] = __builtin_amdgcn_mfma_f32_16x16x32_bf16(ah, whi[q][s], acc[q], 0, 0, 0);
                acc[q] = __builtin_amdgcn_mfma_f32_16x16x32_bf16(al, whi[q][s], acc[q], 0, 0, 0);
                acc[q] = __builtin_amdgcn_mfma_f32_16x16x32_bf16(ah, wlo[q][s], acc[q], 0, 0, 0);
            }
        }
        // C/D layout: col = lane&15, row = quad*4 + reg -> xch[t&1][wave][gate][col][row]
        float* xc = xch[t & 1];
#pragma unroll
        for (int q = 0; q < 4; ++q)
            *(f32x4*)&xc[((wv * 4 + q) * 16 + l16) * 20 + quad * 4] = acc[q];
        __syncthreads();              // the ONLY barrier per step

        // ---- gates (one (er,ec) element per thread), fp32 ----
        float pre[4];
#pragma unroll
        for (int q = 0; q < 4; ++q) {
            float p = bias[q];
#pragma unroll
            for (int ww = 0; ww < 4; ++ww) p += xc[((ww * 4 + q) * 16 + ec) * 20 + er];
            pre[q] = p;
        }
        float fg = sigm(pre[0]);
        float ig = sigm(pre[1]);
        float gg = tanh_(pre[2]);
        float og = sigm(pre[3]);
        cst = fg * cst + ig * gg;
        float hv = og * tanh_(cst);

        // h first (critical path), then out
        u16 hh = f2bf(hv);
        u16 hl = f2bf(hv - bf2f(hh));
        __hip_atomic_store(hout + (size_t)(t & 1) * (BB * HH),
                           ((u64)(u32)(t + 1) << 32) | (u64)pack2(hh, hl),
                           __ATOMIC_RELAXED, __HIP_MEMORY_SCOPE_AGENT);
        out[(size_t)t * (BB * HH) + gidx] = hv;             // outputs[t], exact fp32
        if (t == TT - 1) {
            out[(size_t)TT * (BB * HH) + gidx] = hv;                  // hx
            out[(size_t)TT * (BB * HH) + BB * HH + gidx] = cst;       // cx
        }
        // no trailing barrier: next-step staging is wave-private, xchg is dbuf'd,
        // and the t+1 poll is the inter-block sync.
    }
}

extern "C" void kernel_launch(void* const* d_in, const int* in_sizes, int n_in,
                              void* d_out, int out_size, void* d_ws, size_t ws_size,
                              hipStream_t stream) {
    (void)in_sizes; (void)n_in; (void)out_size; (void)ws_size;
    const float* x   = (const float*)d_in[0];
    const float* Wf  = (const float*)d_in[1];
    const float* bfv = (const float*)d_in[2];
    const float* Wi  = (const float*)d_in[3];
    const float* biv = (const float*)d_in[4];
    const float* Wg  = (const float*)d_in[5];
    const float* bgv = (const float*)d_in[6];
    const float* Wo  = (const float*)d_in[7];
    const float* bov = (const float*)d_in[8];

    u64* hbuf = (u64*)d_ws;   // 2 slots x [128][512] x u64 {tag | hi|lo} = 1 MiB

    // Clear tags every launch (captured in graph): a stale tag==t from a prior
    // launch would satisfy the t=TT-1 poll with old data. tag 0 never matches.
    hipMemsetAsync(d_ws, 0, (size_t)2 * BB * HH * 8, stream);
    lstm_fused<<<dim3(256), dim3(256), 0, stream>>>(x, Wf, bfv, Wi, biv, Wg, bgv, Wo, bov,
                                                    (float*)d_out, hbuf);
}